// Round 5
// baseline (327.404 us; speedup 1.0000x reference)
//
#include <hip/hip_runtime.h>
#include <hip/hip_bf16.h>

#define LN_EPS 1e-5f
#define SLOPE 0.01f

typedef short bf16x8 __attribute__((ext_vector_type(8)));
typedef float f32x4 __attribute__((ext_vector_type(4)));

// ---------------------------------------------------------------------------
// Kernel 1: blockIdx.y==0 -> U[i,d] = robot[i]@W1[0:256] + lang@W1[256:320]
//           blockIdx.y==1 -> V[i,d] = object[i]@W1[320:576] + lang@W1[576:640] + b1
// stats layout: [0..511]=sU, [512..1023]=qU, [1024..1535]=sV, [1536..2047]=qV
// ---------------------------------------------------------------------------
__global__ __launch_bounds__(320) void precompute_uv(
    const float* __restrict__ robot, const float* __restrict__ object,
    const float* __restrict__ lang, const float* __restrict__ W1,
    const float* __restrict__ b1, float* __restrict__ U, float* __restrict__ V,
    __hip_bfloat16* __restrict__ Ub, __hip_bfloat16* __restrict__ Vb,
    float* __restrict__ stats)
{
  __shared__ float red[5][2];
  const int i = blockIdx.x;
  const int d = threadIdx.x;
  const int isV = blockIdx.y;
  const float* __restrict__ src   = isV ? object : robot;
  const float* __restrict__ Wbase = W1 + (isV ? 320 * 320 : 0);

  float acc = 0.f;
#pragma unroll 8
  for (int k = 0; k < 256; ++k)
    acc = fmaf(src[i * 256 + k], Wbase[k * 320 + d], acc);
#pragma unroll 8
  for (int l = 0; l < 64; ++l)
    acc = fmaf(lang[l], Wbase[(256 + l) * 320 + d], acc);
  if (isV) acc += b1[d];

  (isV ? V : U)[i * 320 + d] = acc;
  (isV ? Vb : Ub)[i * 320 + d] = __float2bfloat16(acc);

  float s = acc, q = acc * acc;
#pragma unroll
  for (int m = 1; m < 64; m <<= 1) {
    s += __shfl_xor(s, m);
    q += __shfl_xor(q, m);
  }
  const int w = d >> 6, lane = d & 63;
  if (lane == 0) { red[w][0] = s; red[w][1] = q; }
  __syncthreads();
  if (d == 0) {
    float s0 = 0.f, q0 = 0.f;
    for (int t = 0; t < 5; ++t) { s0 += red[t][0]; q0 += red[t][1]; }
    stats[isV * 1024 + i] = s0;
    stats[isV * 1024 + 512 + i] = q0;
  }
}

// ---------------------------------------------------------------------------
// Kernel 2: blocks 0..255: DOT[i][j] = dot(U[i],V[j]) via bf16 MFMA
//           blocks 256..355: LDS-tiled transpose W2T[d][k] = bf16(W2[k][d])
// ---------------------------------------------------------------------------
__global__ __launch_bounds__(256) void dot_and_transpose(
    const __hip_bfloat16* __restrict__ Ub, const __hip_bfloat16* __restrict__ Vb,
    float* __restrict__ DOT, const float* __restrict__ W2,
    __hip_bfloat16* __restrict__ W2T)
{
  if (blockIdx.x < 256) {
    const int w = threadIdx.x >> 6, lane = threadIdx.x & 63;
    const int id = blockIdx.x * 4 + w;
    const int ti = id >> 5, tj = id & 31;
    const int r16 = lane & 15, g = lane >> 4;
    f32x4 acc = (f32x4){0.f, 0.f, 0.f, 0.f};
    const __hip_bfloat16* __restrict__ A = Ub + (ti * 16 + r16) * 320;
    const __hip_bfloat16* __restrict__ B = Vb + (tj * 16 + r16) * 320;
#pragma unroll
    for (int kk = 0; kk < 10; ++kk) {
      bf16x8 a = *(const bf16x8*)(A + kk * 32 + g * 8);
      bf16x8 b = *(const bf16x8*)(B + kk * 32 + g * 8);
      acc = __builtin_amdgcn_mfma_f32_16x16x32_bf16(a, b, acc, 0, 0, 0);
    }
#pragma unroll
    for (int r = 0; r < 4; ++r)
      DOT[(ti * 16 + g * 4 + r) * 512 + tj * 16 + r16] = acc[r];
  } else {
    __shared__ float tile[32][33];
    const int t = blockIdx.x - 256;       // 0..99
    const int d0 = (t % 10) * 32, k0 = (t / 10) * 32;
    const int tx = threadIdx.x & 31, ty = threadIdx.x >> 5;  // ty 0..7
#pragma unroll
    for (int r = 0; r < 32; r += 8)
      tile[ty + r][tx] = W2[(k0 + ty + r) * 320 + d0 + tx];
    __syncthreads();
#pragma unroll
    for (int r = 0; r < 32; r += 8)
      W2T[(d0 + ty + r) * 320 + k0 + tx] = __float2bfloat16(tile[tx][ty + r]);
  }
}

// ---------------------------------------------------------------------------
// Kernel 3: fused. 256 thr (4 waves), tile (i, 32 j's)  [j-tile halved for
// occupancy: LDS ~26 KB -> 6 blocks/CU vs 3 at 64-row tiles].
// wave w owns ALL 32 rows x cols [w*80, w*80+80): mf=2, nf=5, acc=40 VGPR.
// B gathered from global W2T (L2-hot, unique per wave -> no duplication).
// h1 LDS: linear 640B rows, byte XOR (row&7)<<4 swizzle.
// ---------------------------------------------------------------------------
__global__ __launch_bounds__(256) void fused_main(
    const float* __restrict__ U, const float* __restrict__ V,
    const __hip_bfloat16* __restrict__ W2T,
    const float* __restrict__ DOT, const float* __restrict__ stats,
    const float* __restrict__ g1, const float* __restrict__ be1,
    const float* __restrict__ b2, const float* __restrict__ g2,
    const float* __restrict__ be2, const float* __restrict__ W3,
    const float* __restrict__ b3, float* __restrict__ out)
{
  __shared__ __align__(16) __hip_bfloat16 h1[32 * 320];   // 20 KB
  __shared__ __align__(16) float U_lds[320], g1_lds[320], be1_lds[320];
  __shared__ float mu_lds[32], rs_lds[32];
  __shared__ float part[32][4][2];
  __shared__ float pdot[32][4];

  const int i   = blockIdx.x;
  const int j0  = blockIdx.y * 32;
  const int tid = threadIdx.x;
  const int lane = tid & 63;
  const int w    = tid >> 6;
  const int r16  = lane & 15;
  const int g    = lane >> 4;

  // ---- init: stage U row, g1, be1; algebraic LN1 stats
  for (int t = tid; t < 320; t += 256) {
    U_lds[t]   = U[i * 320 + t];
    g1_lds[t]  = g1[t];
    be1_lds[t] = be1[t];
  }
  if (tid >= 224) {
    const int r = tid - 224;   // 0..31
    const float sU = stats[i],             qU = stats[512 + i];
    const float sV = stats[1024 + j0 + r], qV = stats[1536 + j0 + r];
    const float dt = DOT[i * 512 + j0 + r];
    const float mu = (sU + sV) * (1.f / 320.f);
    const float var = (qU + 2.f * dt + qV) * (1.f / 320.f) - mu * mu;
    mu_lds[r] = mu;
    rs_lds[r] = rsqrtf(var + LN_EPS);
  }
  __syncthreads();

  // ---- Phase 1: elementwise LN1 + leaky -> h1. 8 threads per row, 40 elems.
  {
    const int row = tid >> 3, seg = tid & 7;
    const float* __restrict__ Vrow = V + (j0 + row) * 320 + seg * 40;
    const float rs = rs_lds[row];
    const float murs = mu_lds[row] * rs;
    const unsigned swz = (unsigned)((row & 7) << 4);
    const unsigned base = (unsigned)row * 640u + (unsigned)seg * 80u;
#pragma unroll
    for (int m = 0; m < 5; ++m) {
      const int d = seg * 40 + m * 8;
      const f32x4 va = *(const f32x4*)(Vrow + m * 8);
      const f32x4 vb = *(const f32x4*)(Vrow + m * 8 + 4);
      const f32x4 ua = *(const f32x4*)&U_lds[d];
      const f32x4 ub = *(const f32x4*)&U_lds[d + 4];
      const f32x4 ga = *(const f32x4*)&g1_lds[d];
      const f32x4 gb = *(const f32x4*)&g1_lds[d + 4];
      const f32x4 ea = *(const f32x4*)&be1_lds[d];
      const f32x4 eb = *(const f32x4*)&be1_lds[d + 4];
      union { bf16x8 v; __hip_bfloat16 e[8]; } pk;
#pragma unroll
      for (int e = 0; e < 4; ++e) {
        const float x = ua[e] + va[e];
        float hv = fmaf(fmaf(x, rs, -murs), ga[e], ea[e]);
        hv = fmaxf(hv, SLOPE * hv);
        pk.e[e] = __float2bfloat16(hv);
      }
#pragma unroll
      for (int e = 0; e < 4; ++e) {
        const float x = ub[e] + vb[e];
        float hv = fmaf(fmaf(x, rs, -murs), gb[e], eb[e]);
        hv = fmaxf(hv, SLOPE * hv);
        pk.e[4 + e] = __float2bfloat16(hv);
      }
      *(bf16x8*)((char*)h1 + ((base + (unsigned)m * 16u) ^ swz)) = pk.v;
    }
  }
  __syncthreads();

  // ---- Phase 2: GEMM. wave w: rows 0..31 (mf=2), cols w*80..+80 (nf=5).
  const int wc = w;
  f32x4 acc[2][5];
#pragma unroll
  for (int mf = 0; mf < 2; ++mf)
#pragma unroll
    for (int nf = 0; nf < 5; ++nf)
      acc[mf][nf] = (f32x4){0.f, 0.f, 0.f, 0.f};

  const __hip_bfloat16* __restrict__ Bbase = W2T + (wc * 80 + r16) * 320;
  const unsigned swzA = (unsigned)((r16 & 7) << 4);
  unsigned arow[2];
#pragma unroll
  for (int mf = 0; mf < 2; ++mf)
    arow[mf] = (unsigned)(mf * 16 + r16) * 640u;

#pragma unroll
  for (int kk = 0; kk < 10; ++kk) {
    const unsigned k2 = (unsigned)((kk * 32 + g * 8) * 2);
    bf16x8 a[2];
#pragma unroll
    for (int mf = 0; mf < 2; ++mf)
      a[mf] = *(const bf16x8*)((const char*)h1 + ((arow[mf] + k2) ^ swzA));
#pragma unroll
    for (int nf = 0; nf < 5; ++nf) {
      const bf16x8 b = *(const bf16x8*)(Bbase + nf * 16 * 320 + kk * 32 + g * 8);
#pragma unroll
      for (int mf = 0; mf < 2; ++mf)
        acc[mf][nf] = __builtin_amdgcn_mfma_f32_16x16x32_bf16(
            a[mf], b, acc[mf][nf], 0, 0, 0);
    }
  }

  // ---- epilogue params (global, L2-hot)
  float b2c[5], g2c[5], be2c[5], w3c[5];
#pragma unroll
  for (int nf = 0; nf < 5; ++nf) {
    const int col = wc * 80 + nf * 16 + r16;
    b2c[nf]  = b2[col];
    g2c[nf]  = g2[col];
    be2c[nf] = be2[col];
    w3c[nf]  = W3[col];
  }
#pragma unroll
  for (int nf = 0; nf < 5; ++nf)
#pragma unroll
    for (int mf = 0; mf < 2; ++mf)
#pragma unroll
      for (int r = 0; r < 4; ++r)
        acc[mf][nf][r] += b2c[nf];

  // ---- LN2 stats. global row = mf*16 + g*4 + r
#pragma unroll
  for (int mf = 0; mf < 2; ++mf) {
#pragma unroll
    for (int r = 0; r < 4; ++r) {
      float s = 0.f, q = 0.f;
#pragma unroll
      for (int nf = 0; nf < 5; ++nf) {
        const float v = acc[mf][nf][r];
        s += v;
        q = fmaf(v, v, q);
      }
#pragma unroll
      for (int m = 1; m < 16; m <<= 1) {
        s += __shfl_xor(s, m);
        q += __shfl_xor(q, m);
      }
      if (r16 == 0) {
        const int row = mf * 16 + g * 4 + r;
        part[row][wc][0] = s;
        part[row][wc][1] = q;
      }
    }
  }
  __syncthreads();

  // ---- LN2 apply + leaky + dot W3
#pragma unroll
  for (int mf = 0; mf < 2; ++mf) {
#pragma unroll
    for (int r = 0; r < 4; ++r) {
      const int row = mf * 16 + g * 4 + r;
      const float s = part[row][0][0] + part[row][1][0] +
                      part[row][2][0] + part[row][3][0];
      const float q = part[row][0][1] + part[row][1][1] +
                      part[row][2][1] + part[row][3][1];
      const float mu  = s * (1.f / 320.f);
      const float var = q * (1.f / 320.f) - mu * mu;
      const float rs  = rsqrtf(var + LN_EPS);
      const float murs = mu * rs;
      float dsum = 0.f;
#pragma unroll
      for (int nf = 0; nf < 5; ++nf) {
        float v = fmaf(fmaf(acc[mf][nf][r], rs, -murs), g2c[nf], be2c[nf]);
        v = fmaxf(v, SLOPE * v);
        dsum = fmaf(v, w3c[nf], dsum);
      }
#pragma unroll
      for (int m = 1; m < 16; m <<= 1)
        dsum += __shfl_xor(dsum, m);
      if (r16 == 0)
        pdot[row][wc] = dsum;
    }
  }
  __syncthreads();

  if (tid < 32) {
    const float tot = pdot[tid][0] + pdot[tid][1] + pdot[tid][2] +
                      pdot[tid][3] + b3[0];
    out[i * 512 + j0 + tid] = fabsf(tot);
  }
}

// ---------------------------------------------------------------------------
extern "C" void kernel_launch(void* const* d_in, const int* in_sizes, int n_in,
                              void* d_out, int out_size, void* d_ws, size_t ws_size,
                              hipStream_t stream) {
  const float* robot  = (const float*)d_in[0];
  const float* object = (const float*)d_in[1];
  const float* lang   = (const float*)d_in[2];
  const float* W1  = (const float*)d_in[3];
  const float* b1  = (const float*)d_in[4];
  const float* g1  = (const float*)d_in[5];
  const float* be1 = (const float*)d_in[6];
  const float* W2  = (const float*)d_in[7];
  const float* b2  = (const float*)d_in[8];
  const float* g2  = (const float*)d_in[9];
  const float* be2 = (const float*)d_in[10];
  const float* W3  = (const float*)d_in[11];
  const float* b3  = (const float*)d_in[12];
  float* out = (float*)d_out;

  float* U     = (float*)d_ws;            // 512*320
  float* V     = U + 512 * 320;           // 512*320
  float* stats = V + 512 * 320;           // 2048
  float* DOT   = stats + 2048;            // 512*512
  __hip_bfloat16* W2T = (__hip_bfloat16*)(DOT + 512 * 512);  // 320*320
  __hip_bfloat16* Ub  = W2T + 320 * 320;  // 512*320
  __hip_bfloat16* Vb  = Ub + 512 * 320;   // 512*320

  precompute_uv<<<dim3(512, 2), 320, 0, stream>>>(robot, object, lang, W1, b1,
                                                  U, V, Ub, Vb, stats);
  dot_and_transpose<<<356, 256, 0, stream>>>(Ub, Vb, DOT, W2, W2T);
  fused_main<<<dim3(512, 16), 256, 0, stream>>>(U, V, W2T, DOT, stats,
                                                g1, be1, b2, g2, be2, W3, b3,
                                                out);
}

// Round 6
// 249.446 us; speedup vs baseline: 1.3125x; 1.3125x over previous
//
#include <hip/hip_runtime.h>
#include <hip/hip_bf16.h>

#define LN_EPS 1e-5f
#define SLOPE 0.01f

typedef short bf16x8 __attribute__((ext_vector_type(8)));
typedef float f32x4 __attribute__((ext_vector_type(4)));

// ---------------------------------------------------------------------------
// Kernel 1: blockIdx.y==0 -> U[i,d] = robot[i]@W1[0:256] + lang@W1[256:320]
//           blockIdx.y==1 -> V[i,d] = object[i]@W1[320:576] + lang@W1[576:640] + b1
// stats layout: [0..511]=sU, [512..1023]=qU, [1024..1535]=sV, [1536..2047]=qV
// ---------------------------------------------------------------------------
__global__ __launch_bounds__(320) void precompute_uv(
    const float* __restrict__ robot, const float* __restrict__ object,
    const float* __restrict__ lang, const float* __restrict__ W1,
    const float* __restrict__ b1, float* __restrict__ U, float* __restrict__ V,
    __hip_bfloat16* __restrict__ Ub, __hip_bfloat16* __restrict__ Vb,
    float* __restrict__ stats)
{
  __shared__ float red[5][2];
  const int i = blockIdx.x;
  const int d = threadIdx.x;
  const int isV = blockIdx.y;
  const float* __restrict__ src   = isV ? object : robot;
  const float* __restrict__ Wbase = W1 + (isV ? 320 * 320 : 0);

  float acc = 0.f;
#pragma unroll 8
  for (int k = 0; k < 256; ++k)
    acc = fmaf(src[i * 256 + k], Wbase[k * 320 + d], acc);
#pragma unroll 8
  for (int l = 0; l < 64; ++l)
    acc = fmaf(lang[l], Wbase[(256 + l) * 320 + d], acc);
  if (isV) acc += b1[d];

  (isV ? V : U)[i * 320 + d] = acc;
  (isV ? Vb : Ub)[i * 320 + d] = __float2bfloat16(acc);

  float s = acc, q = acc * acc;
#pragma unroll
  for (int m = 1; m < 64; m <<= 1) {
    s += __shfl_xor(s, m);
    q += __shfl_xor(q, m);
  }
  const int w = d >> 6, lane = d & 63;
  if (lane == 0) { red[w][0] = s; red[w][1] = q; }
  __syncthreads();
  if (d == 0) {
    float s0 = 0.f, q0 = 0.f;
    for (int t = 0; t < 5; ++t) { s0 += red[t][0]; q0 += red[t][1]; }
    stats[isV * 1024 + i] = s0;
    stats[isV * 1024 + 512 + i] = q0;
  }
}

// ---------------------------------------------------------------------------
// Kernel 2: blocks 0..255: DOT[i][j] = dot(U[i],V[j]) via bf16 MFMA
//           blocks 256..355: W2 -> W2F fragment-major bf16:
//   W2F[((kk*20 + frag)*512) + lane*8 + e] = W2[(kk*32 + (lane>>4)*8 + e)*320
//                                               + frag*16 + (lane&15)]
//   so a wave's B-fragment load is base + lane*16B (fully coalesced 1KB).
// ---------------------------------------------------------------------------
__global__ __launch_bounds__(256) void dot_and_reorder(
    const __hip_bfloat16* __restrict__ Ub, const __hip_bfloat16* __restrict__ Vb,
    float* __restrict__ DOT, const float* __restrict__ W2,
    __hip_bfloat16* __restrict__ W2F)
{
  if (blockIdx.x < 256) {
    const int w = threadIdx.x >> 6, lane = threadIdx.x & 63;
    const int id = blockIdx.x * 4 + w;
    const int ti = id >> 5, tj = id & 31;
    const int r16 = lane & 15, g = lane >> 4;
    f32x4 acc = (f32x4){0.f, 0.f, 0.f, 0.f};
    const __hip_bfloat16* __restrict__ A = Ub + (ti * 16 + r16) * 320;
    const __hip_bfloat16* __restrict__ B = Vb + (tj * 16 + r16) * 320;
#pragma unroll
    for (int kk = 0; kk < 10; ++kk) {
      bf16x8 a = *(const bf16x8*)(A + kk * 32 + g * 8);
      bf16x8 b = *(const bf16x8*)(B + kk * 32 + g * 8);
      acc = __builtin_amdgcn_mfma_f32_16x16x32_bf16(a, b, acc, 0, 0, 0);
    }
#pragma unroll
    for (int r = 0; r < 4; ++r)
      DOT[(ti * 16 + g * 4 + r) * 512 + tj * 16 + r16] = acc[r];
  } else {
    __shared__ float tile[32][33];
    const int t = blockIdx.x - 256;       // 0..99
    const int d0 = (t % 10) * 32;         // col base (2 frags)
    const int kk = t / 10;                // k-slice
    const int tx = threadIdx.x & 31, ty = threadIdx.x >> 5;  // ty 0..7
#pragma unroll
    for (int r = 0; r < 32; r += 8)
      tile[ty + r][tx] = W2[((kk * 32) + ty + r) * 320 + d0 + tx];
    __syncthreads();
    // 256 threads -> 2 frags x 64 lanes x 2 halves (4 bf16 each)
    const int fl   = threadIdx.x >> 7;        // frag_local 0..1
    const int l    = (threadIdx.x >> 1) & 63; // lane
    const int half = threadIdx.x & 1;         // 0..1
    const int frag = (d0 >> 4) + fl;
    __hip_bfloat16* dst = W2F + ((kk * 20 + frag) * 512) + l * 8 + half * 4;
#pragma unroll
    for (int e = 0; e < 4; ++e)
      dst[e] = __float2bfloat16(tile[(l >> 4) * 8 + half * 4 + e]
                                    [fl * 16 + (l & 15)]);
  }
}

// ---------------------------------------------------------------------------
// Kernel 3: fused. 256 thr (4 waves), tile (i, 64 j's).
// wave w owns ALL 64 rows x cols [w*80, w*80+80): mf=4, nf=5, acc=80 VGPR.
// B loaded from fragment-major W2F: one coalesced 1KB load per fragment.
// h1 LDS: linear 640B rows, byte XOR (row&7)<<4 swizzle.
// ---------------------------------------------------------------------------
__global__ __launch_bounds__(256) void fused_main(
    const float* __restrict__ U, const float* __restrict__ V,
    const __hip_bfloat16* __restrict__ W2F,
    const float* __restrict__ DOT, const float* __restrict__ stats,
    const float* __restrict__ g1, const float* __restrict__ be1,
    const float* __restrict__ b2, const float* __restrict__ g2,
    const float* __restrict__ be2, const float* __restrict__ W3,
    const float* __restrict__ b3, float* __restrict__ out)
{
  __shared__ __align__(16) __hip_bfloat16 h1[64 * 320];   // 40 KB
  __shared__ __align__(16) float U_lds[320], g1_lds[320], be1_lds[320];
  __shared__ float mu_lds[64], rs_lds[64];
  __shared__ float part[64][4][2];
  __shared__ float pdot[64][4];

  const int i   = blockIdx.x;
  const int j0  = blockIdx.y * 64;
  const int tid = threadIdx.x;
  const int lane = tid & 63;
  const int w    = tid >> 6;
  const int r16  = lane & 15;
  const int g    = lane >> 4;

  // ---- init: stage U row, g1, be1; algebraic LN1 stats
  for (int t = tid; t < 320; t += 256) {
    U_lds[t]   = U[i * 320 + t];
    g1_lds[t]  = g1[t];
    be1_lds[t] = be1[t];
  }
  if (tid >= 192) {
    const int r = tid - 192;   // 0..63
    const float sU = stats[i],             qU = stats[512 + i];
    const float sV = stats[1024 + j0 + r], qV = stats[1536 + j0 + r];
    const float dt = DOT[i * 512 + j0 + r];
    const float mu = (sU + sV) * (1.f / 320.f);
    const float var = (qU + 2.f * dt + qV) * (1.f / 320.f) - mu * mu;
    mu_lds[r] = mu;
    rs_lds[r] = rsqrtf(var + LN_EPS);
  }
  __syncthreads();

  // ---- Phase 1: elementwise LN1 + leaky -> h1. 4 threads per row.
  {
    const int row = tid >> 2, seg = tid & 3;
    const float* __restrict__ Vrow = V + (j0 + row) * 320 + seg * 80;
    const float rs = rs_lds[row];
    const float murs = mu_lds[row] * rs;
    const unsigned swz = (unsigned)((row & 7) << 4);
    const unsigned base = (unsigned)row * 640u + (unsigned)seg * 160u;
#pragma unroll
    for (int m = 0; m < 10; ++m) {
      const int d = seg * 80 + m * 8;
      const f32x4 va = *(const f32x4*)(Vrow + m * 8);
      const f32x4 vb = *(const f32x4*)(Vrow + m * 8 + 4);
      const f32x4 ua = *(const f32x4*)&U_lds[d];
      const f32x4 ub = *(const f32x4*)&U_lds[d + 4];
      const f32x4 ga = *(const f32x4*)&g1_lds[d];
      const f32x4 gb = *(const f32x4*)&g1_lds[d + 4];
      const f32x4 ea = *(const f32x4*)&be1_lds[d];
      const f32x4 eb = *(const f32x4*)&be1_lds[d + 4];
      union { bf16x8 v; __hip_bfloat16 e[8]; } pk;
#pragma unroll
      for (int e = 0; e < 4; ++e) {
        const float x = ua[e] + va[e];
        float hv = fmaf(fmaf(x, rs, -murs), ga[e], ea[e]);
        hv = fmaxf(hv, SLOPE * hv);
        pk.e[e] = __float2bfloat16(hv);
      }
#pragma unroll
      for (int e = 0; e < 4; ++e) {
        const float x = ub[e] + vb[e];
        float hv = fmaf(fmaf(x, rs, -murs), gb[e], eb[e]);
        hv = fmaxf(hv, SLOPE * hv);
        pk.e[4 + e] = __float2bfloat16(hv);
      }
      *(bf16x8*)((char*)h1 + ((base + (unsigned)m * 16u) ^ swz)) = pk.v;
    }
  }
  __syncthreads();

  // ---- Phase 2: GEMM. wave w: rows 0..63 (mf=4), cols w*80..+80 (nf=5).
  const int wc = w;
  f32x4 acc[4][5];
#pragma unroll
  for (int mf = 0; mf < 4; ++mf)
#pragma unroll
    for (int nf = 0; nf < 5; ++nf)
      acc[mf][nf] = (f32x4){0.f, 0.f, 0.f, 0.f};

  // fragment-major B: frag = wc*5 + nf, addr = ((kk*20+frag)*512) + lane*8
  const __hip_bfloat16* __restrict__ Bf = W2F + (size_t)(wc * 5) * 512 + lane * 8;
  const unsigned swzA = (unsigned)((r16 & 7) << 4);
  unsigned arow[4];
#pragma unroll
  for (int mf = 0; mf < 4; ++mf)
    arow[mf] = (unsigned)(mf * 16 + r16) * 640u;

#pragma unroll
  for (int kk = 0; kk < 10; ++kk) {
    const unsigned k2 = (unsigned)((kk * 32 + g * 8) * 2);
    bf16x8 a[4];
#pragma unroll
    for (int mf = 0; mf < 4; ++mf)
      a[mf] = *(const bf16x8*)((const char*)h1 + ((arow[mf] + k2) ^ swzA));
#pragma unroll
    for (int nf = 0; nf < 5; ++nf) {
      const bf16x8 b = *(const bf16x8*)(Bf + (kk * 20 + nf) * 512);
#pragma unroll
      for (int mf = 0; mf < 4; ++mf)
        acc[mf][nf] = __builtin_amdgcn_mfma_f32_16x16x32_bf16(
            a[mf], b, acc[mf][nf], 0, 0, 0);
    }
  }

  // ---- epilogue params (global, L2-hot)
  float b2c[5], g2c[5], be2c[5], w3c[5];
#pragma unroll
  for (int nf = 0; nf < 5; ++nf) {
    const int col = wc * 80 + nf * 16 + r16;
    b2c[nf]  = b2[col];
    g2c[nf]  = g2[col];
    be2c[nf] = be2[col];
    w3c[nf]  = W3[col];
  }
#pragma unroll
  for (int nf = 0; nf < 5; ++nf)
#pragma unroll
    for (int mf = 0; mf < 4; ++mf)
#pragma unroll
      for (int r = 0; r < 4; ++r)
        acc[mf][nf][r] += b2c[nf];

  // ---- LN2 stats. global row = mf*16 + g*4 + r
#pragma unroll
  for (int mf = 0; mf < 4; ++mf) {
#pragma unroll
    for (int r = 0; r < 4; ++r) {
      float s = 0.f, q = 0.f;
#pragma unroll
      for (int nf = 0; nf < 5; ++nf) {
        const float v = acc[mf][nf][r];
        s += v;
        q = fmaf(v, v, q);
      }
#pragma unroll
      for (int m = 1; m < 16; m <<= 1) {
        s += __shfl_xor(s, m);
        q += __shfl_xor(q, m);
      }
      if (r16 == 0) {
        const int row = mf * 16 + g * 4 + r;
        part[row][wc][0] = s;
        part[row][wc][1] = q;
      }
    }
  }
  __syncthreads();

  // ---- LN2 apply + leaky + dot W3
#pragma unroll
  for (int mf = 0; mf < 4; ++mf) {
#pragma unroll
    for (int r = 0; r < 4; ++r) {
      const int row = mf * 16 + g * 4 + r;
      const float s = part[row][0][0] + part[row][1][0] +
                      part[row][2][0] + part[row][3][0];
      const float q = part[row][0][1] + part[row][1][1] +
                      part[row][2][1] + part[row][3][1];
      const float mu  = s * (1.f / 320.f);
      const float var = q * (1.f / 320.f) - mu * mu;
      const float rs  = rsqrtf(var + LN_EPS);
      const float murs = mu * rs;
      float dsum = 0.f;
#pragma unroll
      for (int nf = 0; nf < 5; ++nf) {
        float v = fmaf(fmaf(acc[mf][nf][r], rs, -murs), g2c[nf], be2c[nf]);
        v = fmaxf(v, SLOPE * v);
        dsum = fmaf(v, w3c[nf], dsum);
      }
#pragma unroll
      for (int m = 1; m < 16; m <<= 1)
        dsum += __shfl_xor(dsum, m);
      if (r16 == 0)
        pdot[row][wc] = dsum;
    }
  }
  __syncthreads();

  if (tid < 64) {
    const float tot = pdot[tid][0] + pdot[tid][1] + pdot[tid][2] +
                      pdot[tid][3] + b3[0];
    out[i * 512 + j0 + tid] = fabsf(tot);
  }
}

// ---------------------------------------------------------------------------
extern "C" void kernel_launch(void* const* d_in, const int* in_sizes, int n_in,
                              void* d_out, int out_size, void* d_ws, size_t ws_size,
                              hipStream_t stream) {
  const float* robot  = (const float*)d_in[0];
  const float* object = (const float*)d_in[1];
  const float* lang   = (const float*)d_in[2];
  const float* W1  = (const float*)d_in[3];
  const float* b1  = (const float*)d_in[4];
  const float* g1  = (const float*)d_in[5];
  const float* be1 = (const float*)d_in[6];
  const float* W2  = (const float*)d_in[7];
  const float* b2  = (const float*)d_in[8];
  const float* g2  = (const float*)d_in[9];
  const float* be2 = (const float*)d_in[10];
  const float* W3  = (const float*)d_in[11];
  const float* b3  = (const float*)d_in[12];
  float* out = (float*)d_out;

  float* U     = (float*)d_ws;            // 512*320
  float* V     = U + 512 * 320;           // 512*320
  float* stats = V + 512 * 320;           // 2048
  float* DOT   = stats + 2048;            // 512*512
  __hip_bfloat16* W2F = (__hip_bfloat16*)(DOT + 512 * 512);  // 320*320 (frag-major)
  __hip_bfloat16* Ub  = W2F + 320 * 320;  // 512*320
  __hip_bfloat16* Vb  = Ub + 512 * 320;   // 512*320

  precompute_uv<<<dim3(512, 2), 320, 0, stream>>>(robot, object, lang, W1, b1,
                                                  U, V, Ub, Vb, stats);
  dot_and_reorder<<<356, 256, 0, stream>>>(Ub, Vb, DOT, W2, W2F);
  fused_main<<<dim3(512, 8), 256, 0, stream>>>(U, V, W2F, DOT, stats,
                                               g1, be1, b2, g2, be2, W3, b3,
                                               out);
}

// Round 7
// 215.046 us; speedup vs baseline: 1.5225x; 1.1600x over previous
//
#include <hip/hip_runtime.h>
#include <hip/hip_bf16.h>

#define LN_EPS 1e-5f
#define SLOPE 0.01f

typedef short bf16x8 __attribute__((ext_vector_type(8)));
typedef float f32x4 __attribute__((ext_vector_type(4)));

// ---------------------------------------------------------------------------
// Kernel 1: blockIdx.y==0 -> U[i,d] = robot[i]@W1[0:256] + lang@W1[256:320]
//           blockIdx.y==1 -> V[i,d] = object[i]@W1[320:576] + lang@W1[576:640] + b1
// stats layout: [0..511]=sU, [512..1023]=qU, [1024..1535]=sV, [1536..2047]=qV
// ---------------------------------------------------------------------------
__global__ __launch_bounds__(320) void precompute_uv(
    const float* __restrict__ robot, const float* __restrict__ object,
    const float* __restrict__ lang, const float* __restrict__ W1,
    const float* __restrict__ b1, float* __restrict__ U, float* __restrict__ V,
    __hip_bfloat16* __restrict__ Ub, __hip_bfloat16* __restrict__ Vb,
    float* __restrict__ stats)
{
  __shared__ float red[5][2];
  const int i = blockIdx.x;
  const int d = threadIdx.x;
  const int isV = blockIdx.y;
  const float* __restrict__ src   = isV ? object : robot;
  const float* __restrict__ Wbase = W1 + (isV ? 320 * 320 : 0);

  float acc = 0.f;
#pragma unroll 8
  for (int k = 0; k < 256; ++k)
    acc = fmaf(src[i * 256 + k], Wbase[k * 320 + d], acc);
#pragma unroll 8
  for (int l = 0; l < 64; ++l)
    acc = fmaf(lang[l], Wbase[(256 + l) * 320 + d], acc);
  if (isV) acc += b1[d];

  (isV ? V : U)[i * 320 + d] = acc;
  (isV ? Vb : Ub)[i * 320 + d] = __float2bfloat16(acc);

  float s = acc, q = acc * acc;
#pragma unroll
  for (int m = 1; m < 64; m <<= 1) {
    s += __shfl_xor(s, m);
    q += __shfl_xor(q, m);
  }
  const int w = d >> 6, lane = d & 63;
  if (lane == 0) { red[w][0] = s; red[w][1] = q; }
  __syncthreads();
  if (d == 0) {
    float s0 = 0.f, q0 = 0.f;
    for (int t = 0; t < 5; ++t) { s0 += red[t][0]; q0 += red[t][1]; }
    stats[isV * 1024 + i] = s0;
    stats[isV * 1024 + 512 + i] = q0;
  }
}

// ---------------------------------------------------------------------------
// Kernel 2: blocks 0..255: DOT[i][j] = dot(U[i],V[j]) via bf16 MFMA
//           blocks 256..355: W2 -> W2F fragment-major bf16:
//   W2F[((kk*20 + frag)*512) + lane*8 + e] = W2[(kk*32 + (lane>>4)*8 + e)*320
//                                               + frag*16 + (lane&15)]
//   so a wave's B-fragment load is base + lane*16B (fully coalesced 1KB).
// ---------------------------------------------------------------------------
__global__ __launch_bounds__(256) void dot_and_reorder(
    const __hip_bfloat16* __restrict__ Ub, const __hip_bfloat16* __restrict__ Vb,
    float* __restrict__ DOT, const float* __restrict__ W2,
    __hip_bfloat16* __restrict__ W2F)
{
  if (blockIdx.x < 256) {
    const int w = threadIdx.x >> 6, lane = threadIdx.x & 63;
    const int id = blockIdx.x * 4 + w;
    const int ti = id >> 5, tj = id & 31;
    const int r16 = lane & 15, g = lane >> 4;
    f32x4 acc = (f32x4){0.f, 0.f, 0.f, 0.f};
    const __hip_bfloat16* __restrict__ A = Ub + (ti * 16 + r16) * 320;
    const __hip_bfloat16* __restrict__ B = Vb + (tj * 16 + r16) * 320;
#pragma unroll
    for (int kk = 0; kk < 10; ++kk) {
      bf16x8 a = *(const bf16x8*)(A + kk * 32 + g * 8);
      bf16x8 b = *(const bf16x8*)(B + kk * 32 + g * 8);
      acc = __builtin_amdgcn_mfma_f32_16x16x32_bf16(a, b, acc, 0, 0, 0);
    }
#pragma unroll
    for (int r = 0; r < 4; ++r)
      DOT[(ti * 16 + g * 4 + r) * 512 + tj * 16 + r16] = acc[r];
  } else {
    __shared__ float tile[32][33];
    const int t = blockIdx.x - 256;       // 0..99
    const int d0 = (t % 10) * 32;         // col base (2 frags)
    const int kk = t / 10;                // k-slice
    const int tx = threadIdx.x & 31, ty = threadIdx.x >> 5;  // ty 0..7
#pragma unroll
    for (int r = 0; r < 32; r += 8)
      tile[ty + r][tx] = W2[((kk * 32) + ty + r) * 320 + d0 + tx];
    __syncthreads();
    // 256 threads -> 2 frags x 64 lanes x 2 halves (4 bf16 each)
    const int fl   = threadIdx.x >> 7;        // frag_local 0..1
    const int l    = (threadIdx.x >> 1) & 63; // lane
    const int half = threadIdx.x & 1;         // 0..1
    const int frag = (d0 >> 4) + fl;
    __hip_bfloat16* dst = W2F + ((kk * 20 + frag) * 512) + l * 8 + half * 4;
#pragma unroll
    for (int e = 0; e < 4; ++e)
      dst[e] = __float2bfloat16(tile[(l >> 4) * 8 + half * 4 + e]
                                    [fl * 16 + (l & 15)]);
  }
}

// ---------------------------------------------------------------------------
// Kernel 3: fused. 256 thr (4 waves), tile (i, 64 j's).
// wave w owns ALL 64 rows x cols [w*80, w*80+80): mf=4, nf=5, acc=80 VGPR.
// B loaded from fragment-major W2F, double-buffered across K-steps.
// __launch_bounds__(256,3): LDS caps residency at 3 blocks/CU anyway, so
// let the allocator use up to ~170 VGPRs for prefetch depth.
// h1 LDS: linear 640B rows, byte XOR (row&7)<<4 swizzle.
// ---------------------------------------------------------------------------
__global__ __launch_bounds__(256, 3) void fused_main(
    const float* __restrict__ U, const float* __restrict__ V,
    const __hip_bfloat16* __restrict__ W2F,
    const float* __restrict__ DOT, const float* __restrict__ stats,
    const float* __restrict__ g1, const float* __restrict__ be1,
    const float* __restrict__ b2, const float* __restrict__ g2,
    const float* __restrict__ be2, const float* __restrict__ W3,
    const float* __restrict__ b3, float* __restrict__ out)
{
  __shared__ __align__(16) __hip_bfloat16 h1[64 * 320];   // 40 KB
  __shared__ __align__(16) float U_lds[320], g1_lds[320], be1_lds[320];
  __shared__ float mu_lds[64], rs_lds[64];
  __shared__ float part[64][4][2];
  __shared__ float pdot[64][4];

  const int i   = blockIdx.x;
  const int j0  = blockIdx.y * 64;
  const int tid = threadIdx.x;
  const int lane = tid & 63;
  const int w    = tid >> 6;
  const int r16  = lane & 15;
  const int g    = lane >> 4;

  // ---- init: stage U row, g1, be1; algebraic LN1 stats
  for (int t = tid; t < 320; t += 256) {
    U_lds[t]   = U[i * 320 + t];
    g1_lds[t]  = g1[t];
    be1_lds[t] = be1[t];
  }
  if (tid >= 192) {
    const int r = tid - 192;   // 0..63
    const float sU = stats[i],             qU = stats[512 + i];
    const float sV = stats[1024 + j0 + r], qV = stats[1536 + j0 + r];
    const float dt = DOT[i * 512 + j0 + r];
    const float mu = (sU + sV) * (1.f / 320.f);
    const float var = (qU + 2.f * dt + qV) * (1.f / 320.f) - mu * mu;
    mu_lds[r] = mu;
    rs_lds[r] = rsqrtf(var + LN_EPS);
  }
  __syncthreads();

  // ---- Phase 1: elementwise LN1 + leaky -> h1. 4 threads per row.
  {
    const int row = tid >> 2, seg = tid & 3;
    const float* __restrict__ Vrow = V + (j0 + row) * 320 + seg * 80;
    const float rs = rs_lds[row];
    const float murs = mu_lds[row] * rs;
    const unsigned swz = (unsigned)((row & 7) << 4);
    const unsigned base = (unsigned)row * 640u + (unsigned)seg * 160u;
#pragma unroll
    for (int m = 0; m < 10; ++m) {
      const int d = seg * 80 + m * 8;
      const f32x4 va = *(const f32x4*)(Vrow + m * 8);
      const f32x4 vb = *(const f32x4*)(Vrow + m * 8 + 4);
      const f32x4 ua = *(const f32x4*)&U_lds[d];
      const f32x4 ub = *(const f32x4*)&U_lds[d + 4];
      const f32x4 ga = *(const f32x4*)&g1_lds[d];
      const f32x4 gb = *(const f32x4*)&g1_lds[d + 4];
      const f32x4 ea = *(const f32x4*)&be1_lds[d];
      const f32x4 eb = *(const f32x4*)&be1_lds[d + 4];
      union { bf16x8 v; __hip_bfloat16 e[8]; } pk;
#pragma unroll
      for (int e = 0; e < 4; ++e) {
        const float x = ua[e] + va[e];
        float hv = fmaf(fmaf(x, rs, -murs), ga[e], ea[e]);
        hv = fmaxf(hv, SLOPE * hv);
        pk.e[e] = __float2bfloat16(hv);
      }
#pragma unroll
      for (int e = 0; e < 4; ++e) {
        const float x = ub[e] + vb[e];
        float hv = fmaf(fmaf(x, rs, -murs), gb[e], eb[e]);
        hv = fmaxf(hv, SLOPE * hv);
        pk.e[4 + e] = __float2bfloat16(hv);
      }
      *(bf16x8*)((char*)h1 + ((base + (unsigned)m * 16u) ^ swz)) = pk.v;
    }
  }
  __syncthreads();

  // ---- Phase 2: GEMM. wave w: rows 0..63 (mf=4), cols w*80..+80 (nf=5).
  const int wc = w;
  f32x4 acc[4][5];
#pragma unroll
  for (int mf = 0; mf < 4; ++mf)
#pragma unroll
    for (int nf = 0; nf < 5; ++nf)
      acc[mf][nf] = (f32x4){0.f, 0.f, 0.f, 0.f};

  // fragment-major B: frag = wc*5 + nf, addr = ((kk*20+frag)*512) + lane*8
  const __hip_bfloat16* __restrict__ Bf = W2F + (size_t)(wc * 5) * 512 + lane * 8;
  const unsigned swzA = (unsigned)((r16 & 7) << 4);
  unsigned arow[4];
#pragma unroll
  for (int mf = 0; mf < 4; ++mf)
    arow[mf] = (unsigned)(mf * 16 + r16) * 640u;

  // double-buffered B fragments (static indices: loop fully unrolled)
  bf16x8 bbuf[2][5];
#pragma unroll
  for (int nf = 0; nf < 5; ++nf)
    bbuf[0][nf] = *(const bf16x8*)(Bf + nf * 512);

#pragma unroll
  for (int kk = 0; kk < 10; ++kk) {
    const int cur = kk & 1, nxt = cur ^ 1;
    if (kk < 9) {
#pragma unroll
      for (int nf = 0; nf < 5; ++nf)
        bbuf[nxt][nf] = *(const bf16x8*)(Bf + ((kk + 1) * 20 + nf) * 512);
    }
    const unsigned k2 = (unsigned)((kk * 32 + g * 8) * 2);
    bf16x8 a[4];
#pragma unroll
    for (int mf = 0; mf < 4; ++mf)
      a[mf] = *(const bf16x8*)((const char*)h1 + ((arow[mf] + k2) ^ swzA));
#pragma unroll
    for (int nf = 0; nf < 5; ++nf)
#pragma unroll
      for (int mf = 0; mf < 4; ++mf)
        acc[mf][nf] = __builtin_amdgcn_mfma_f32_16x16x32_bf16(
            a[mf], bbuf[cur][nf], acc[mf][nf], 0, 0, 0);
  }

  // ---- epilogue params (global, L2-hot)
  float b2c[5], g2c[5], be2c[5], w3c[5];
#pragma unroll
  for (int nf = 0; nf < 5; ++nf) {
    const int col = wc * 80 + nf * 16 + r16;
    b2c[nf]  = b2[col];
    g2c[nf]  = g2[col];
    be2c[nf] = be2[col];
    w3c[nf]  = W3[col];
  }
#pragma unroll
  for (int nf = 0; nf < 5; ++nf)
#pragma unroll
    for (int mf = 0; mf < 4; ++mf)
#pragma unroll
      for (int r = 0; r < 4; ++r)
        acc[mf][nf][r] += b2c[nf];

  // ---- LN2 stats. global row = mf*16 + g*4 + r
#pragma unroll
  for (int mf = 0; mf < 4; ++mf) {
#pragma unroll
    for (int r = 0; r < 4; ++r) {
      float s = 0.f, q = 0.f;
#pragma unroll
      for (int nf = 0; nf < 5; ++nf) {
        const float v = acc[mf][nf][r];
        s += v;
        q = fmaf(v, v, q);
      }
#pragma unroll
      for (int m = 1; m < 16; m <<= 1) {
        s += __shfl_xor(s, m);
        q += __shfl_xor(q, m);
      }
      if (r16 == 0) {
        const int row = mf * 16 + g * 4 + r;
        part[row][wc][0] = s;
        part[row][wc][1] = q;
      }
    }
  }
  __syncthreads();

  // ---- LN2 apply + leaky + dot W3
#pragma unroll
  for (int mf = 0; mf < 4; ++mf) {
#pragma unroll
    for (int r = 0; r < 4; ++r) {
      const int row = mf * 16 + g * 4 + r;
      const float s = part[row][0][0] + part[row][1][0] +
                      part[row][2][0] + part[row][3][0];
      const float q = part[row][0][1] + part[row][1][1] +
                      part[row][2][1] + part[row][3][1];
      const float mu  = s * (1.f / 320.f);
      const float var = q * (1.f / 320.f) - mu * mu;
      const float rs  = rsqrtf(var + LN_EPS);
      const float murs = mu * rs;
      float dsum = 0.f;
#pragma unroll
      for (int nf = 0; nf < 5; ++nf) {
        float v = fmaf(fmaf(acc[mf][nf][r], rs, -murs), g2c[nf], be2c[nf]);
        v = fmaxf(v, SLOPE * v);
        dsum = fmaf(v, w3c[nf], dsum);
      }
#pragma unroll
      for (int m = 1; m < 16; m <<= 1)
        dsum += __shfl_xor(dsum, m);
      if (r16 == 0)
        pdot[row][wc] = dsum;
    }
  }
  __syncthreads();

  if (tid < 64) {
    const float tot = pdot[tid][0] + pdot[tid][1] + pdot[tid][2] +
                      pdot[tid][3] + b3[0];
    out[i * 512 + j0 + tid] = fabsf(tot);
  }
}

// ---------------------------------------------------------------------------
extern "C" void kernel_launch(void* const* d_in, const int* in_sizes, int n_in,
                              void* d_out, int out_size, void* d_ws, size_t ws_size,
                              hipStream_t stream) {
  const float* robot  = (const float*)d_in[0];
  const float* object = (const float*)d_in[1];
  const float* lang   = (const float*)d_in[2];
  const float* W1  = (const float*)d_in[3];
  const float* b1  = (const float*)d_in[4];
  const float* g1  = (const float*)d_in[5];
  const float* be1 = (const float*)d_in[6];
  const float* W2  = (const float*)d_in[7];
  const float* b2  = (const float*)d_in[8];
  const float* g2  = (const float*)d_in[9];
  const float* be2 = (const float*)d_in[10];
  const float* W3  = (const float*)d_in[11];
  const float* b3  = (const float*)d_in[12];
  float* out = (float*)d_out;

  float* U     = (float*)d_ws;            // 512*320
  float* V     = U + 512 * 320;           // 512*320
  float* stats = V + 512 * 320;           // 2048
  float* DOT   = stats + 2048;            // 512*512
  __hip_bfloat16* W2F = (__hip_bfloat16*)(DOT + 512 * 512);  // 320*320 (frag-major)
  __hip_bfloat16* Ub  = W2F + 320 * 320;  // 512*320
  __hip_bfloat16* Vb  = Ub + 512 * 320;   // 512*320

  precompute_uv<<<dim3(512, 2), 320, 0, stream>>>(robot, object, lang, W1, b1,
                                                  U, V, Ub, Vb, stats);
  dot_and_reorder<<<356, 256, 0, stream>>>(Ub, Vb, DOT, W2, W2F);
  fused_main<<<dim3(512, 8), 256, 0, stream>>>(U, V, W2F, DOT, stats,
                                               g1, be1, b2, g2, be2, W3, b3,
                                               out);
}

// Round 8
// 213.397 us; speedup vs baseline: 1.5342x; 1.0077x over previous
//
#include <hip/hip_runtime.h>
#include <hip/hip_bf16.h>

#define LN_EPS 1e-5f
#define SLOPE 0.01f

typedef short bf16x8 __attribute__((ext_vector_type(8)));
typedef float f32x4 __attribute__((ext_vector_type(4)));

// ---------------------------------------------------------------------------
// Kernel 1 (merged prep):
//  blocks 0..1023:  precompute U/V rows + per-row {sum, sumsq} stats
//     bx>>1 = i, bx&1 = isV
//     U[i,d] = robot[i]@W1[0:256] + lang@W1[256:320]
//     V[i,d] = object[i]@W1[320:576] + lang@W1[576:640] + b1
//     stats: [0..511]=sU, [512..1023]=qU, [1024..1535]=sV, [1536..2047]=qV
//  blocks 1024..1123: W2 -> W2F fragment-major bf16:
//     W2F[((kk*20+frag)*512) + l*8 + e] = W2[(kk*32+(l>>4)*8+e)*320 + frag*16 + (l&15)]
// ---------------------------------------------------------------------------
__global__ __launch_bounds__(320) void prep_kernel(
    const float* __restrict__ robot, const float* __restrict__ object,
    const float* __restrict__ lang, const float* __restrict__ W1,
    const float* __restrict__ b1, const float* __restrict__ W2,
    float* __restrict__ U, float* __restrict__ V,
    float* __restrict__ stats, __hip_bfloat16* __restrict__ W2F)
{
  __shared__ float red[5][2];
  __shared__ float tile[32][33];
  const int bx = blockIdx.x;
  const int tid = threadIdx.x;

  if (bx < 1024) {
    const int i = bx >> 1;
    const int isV = bx & 1;
    const int d = tid;
    const float* __restrict__ src   = isV ? object : robot;
    const float* __restrict__ Wbase = W1 + (isV ? 320 * 320 : 0);

    float acc = 0.f;
#pragma unroll 8
    for (int k = 0; k < 256; ++k)
      acc = fmaf(src[i * 256 + k], Wbase[k * 320 + d], acc);
#pragma unroll 8
    for (int l = 0; l < 64; ++l)
      acc = fmaf(lang[l], Wbase[(256 + l) * 320 + d], acc);
    if (isV) acc += b1[d];

    (isV ? V : U)[i * 320 + d] = acc;

    float s = acc, q = acc * acc;
#pragma unroll
    for (int m = 1; m < 64; m <<= 1) {
      s += __shfl_xor(s, m);
      q += __shfl_xor(q, m);
    }
    const int w = d >> 6, lane = d & 63;
    if (lane == 0) { red[w][0] = s; red[w][1] = q; }
    __syncthreads();
    if (d == 0) {
      float s0 = 0.f, q0 = 0.f;
      for (int t = 0; t < 5; ++t) { s0 += red[t][0]; q0 += red[t][1]; }
      stats[isV * 1024 + i] = s0;
      stats[isV * 1024 + 512 + i] = q0;
    }
  } else {
    const int t = bx - 1024;              // 0..99
    const int d0 = (t % 10) * 32;         // col base (2 frags)
    const int kk = t / 10;                // k-slice
    if (tid < 256) {
      const int tx = tid & 31, ty = tid >> 5;  // ty 0..7
#pragma unroll
      for (int r = 0; r < 32; r += 8)
        tile[ty + r][tx] = W2[((kk * 32) + ty + r) * 320 + d0 + tx];
    }
    __syncthreads();
    if (tid < 256) {
      const int fl   = tid >> 7;        // frag_local 0..1
      const int l    = (tid >> 1) & 63; // lane
      const int half = tid & 1;         // 0..1
      const int frag = (d0 >> 4) + fl;
      __hip_bfloat16* dst = W2F + ((kk * 20 + frag) * 512) + l * 8 + half * 4;
#pragma unroll
      for (int e = 0; e < 4; ++e)
        dst[e] = __float2bfloat16(tile[(l >> 4) * 8 + half * 4 + e]
                                      [fl * 16 + (l & 15)]);
    }
  }
}

// ---------------------------------------------------------------------------
// Kernel 2: fused. 256 thr (4 waves), tile (i, 64 j's).
// Prologue prefetch: V row segment (20xf32x4), row stats, B slice-0 —
// all issued before the first barrier.
// P1 computes the LN1 cross-term dot(U,V) in-register (quad shuffle reduce),
// then elementwise LN1+leaky -> h1 (XOR-swizzled LDS).
// GEMM: wave w owns 64 rows x cols [w*80,w*80+80): mf=4, nf=5, acc=80 VGPR.
// B from fragment-major W2F, double-buffered across K-steps.
// ---------------------------------------------------------------------------
__global__ __launch_bounds__(256, 3) void fused_main(
    const float* __restrict__ U, const float* __restrict__ V,
    const __hip_bfloat16* __restrict__ W2F, const float* __restrict__ stats,
    const float* __restrict__ g1, const float* __restrict__ be1,
    const float* __restrict__ b2, const float* __restrict__ g2,
    const float* __restrict__ be2, const float* __restrict__ W3,
    const float* __restrict__ b3, float* __restrict__ out)
{
  __shared__ __align__(16) __hip_bfloat16 h1[64 * 320];   // 40 KB
  __shared__ __align__(16) float U_lds[320], g1_lds[320], be1_lds[320];
  __shared__ float part[64][4][2];
  __shared__ float pdot[64][4];

  const int i   = blockIdx.x;
  const int j0  = blockIdx.y * 64;
  const int tid = threadIdx.x;
  const int lane = tid & 63;
  const int w    = tid >> 6;
  const int r16  = lane & 15;
  const int g    = lane >> 4;
  const int row  = tid >> 2;   // 0..63  (4 threads per row)
  const int seg  = tid & 3;    // 80-elem segment

  // ---- prologue: issue all global loads before the barrier
  const float* __restrict__ Vrow = V + (j0 + row) * 320 + seg * 80;
  f32x4 vreg[20];
#pragma unroll
  for (int m = 0; m < 20; ++m)
    vreg[m] = *(const f32x4*)(Vrow + m * 4);
  const float sVr = stats[1024 + j0 + row];
  const float qVr = stats[1536 + j0 + row];

  const int wc = w;
  const __hip_bfloat16* __restrict__ Bf = W2F + (size_t)(wc * 5) * 512 + lane * 8;
  bf16x8 bbuf[2][5];
#pragma unroll
  for (int nf = 0; nf < 5; ++nf)
    bbuf[0][nf] = *(const bf16x8*)(Bf + nf * 512);

  for (int t = tid; t < 320; t += 256) {
    U_lds[t]   = U[i * 320 + t];
    g1_lds[t]  = g1[t];
    be1_lds[t] = be1[t];
  }
  const float sU = stats[i], qU = stats[512 + i];
  __syncthreads();

  // ---- P1a: cross-term dot(U[i], V[j]) over this thread's 80 elems
  float dt = 0.f;
#pragma unroll
  for (int m = 0; m < 20; ++m) {
    const f32x4 u = *(const f32x4*)&U_lds[seg * 80 + m * 4];
#pragma unroll
    for (int e = 0; e < 4; ++e)
      dt = fmaf(u[e], vreg[m][e], dt);
  }
  dt += __shfl_xor(dt, 1);
  dt += __shfl_xor(dt, 2);
  const float mu   = (sU + sVr) * (1.f / 320.f);
  const float var  = (qU + 2.f * dt + qVr) * (1.f / 320.f) - mu * mu;
  const float rs   = rsqrtf(var + LN_EPS);
  const float murs = mu * rs;

  // ---- P1b: elementwise LN1 + leaky -> h1
  {
    const unsigned swz  = (unsigned)((row & 7) << 4);
    const unsigned base = (unsigned)row * 640u + (unsigned)seg * 160u;
#pragma unroll
    for (int m = 0; m < 10; ++m) {
      const int d = seg * 80 + m * 8;
      const f32x4 va = vreg[2 * m];
      const f32x4 vb = vreg[2 * m + 1];
      const f32x4 ua = *(const f32x4*)&U_lds[d];
      const f32x4 ub = *(const f32x4*)&U_lds[d + 4];
      const f32x4 ga = *(const f32x4*)&g1_lds[d];
      const f32x4 gb = *(const f32x4*)&g1_lds[d + 4];
      const f32x4 ea = *(const f32x4*)&be1_lds[d];
      const f32x4 eb = *(const f32x4*)&be1_lds[d + 4];
      union { bf16x8 v; __hip_bfloat16 e[8]; } pk;
#pragma unroll
      for (int e = 0; e < 4; ++e) {
        const float x = ua[e] + va[e];
        float hv = fmaf(fmaf(x, rs, -murs), ga[e], ea[e]);
        hv = fmaxf(hv, SLOPE * hv);
        pk.e[e] = __float2bfloat16(hv);
      }
#pragma unroll
      for (int e = 0; e < 4; ++e) {
        const float x = ub[e] + vb[e];
        float hv = fmaf(fmaf(x, rs, -murs), gb[e], eb[e]);
        hv = fmaxf(hv, SLOPE * hv);
        pk.e[4 + e] = __float2bfloat16(hv);
      }
      *(bf16x8*)((char*)h1 + ((base + (unsigned)m * 16u) ^ swz)) = pk.v;
    }
  }
  __syncthreads();

  // ---- P2: GEMM. wave w: rows 0..63 (mf=4), cols w*80..+80 (nf=5).
  f32x4 acc[4][5];
#pragma unroll
  for (int mf = 0; mf < 4; ++mf)
#pragma unroll
    for (int nf = 0; nf < 5; ++nf)
      acc[mf][nf] = (f32x4){0.f, 0.f, 0.f, 0.f};

  const unsigned swzA = (unsigned)((r16 & 7) << 4);
  unsigned arow[4];
#pragma unroll
  for (int mf = 0; mf < 4; ++mf)
    arow[mf] = (unsigned)(mf * 16 + r16) * 640u;

#pragma unroll
  for (int kk = 0; kk < 10; ++kk) {
    const int cur = kk & 1, nxt = cur ^ 1;
    if (kk < 9) {
#pragma unroll
      for (int nf = 0; nf < 5; ++nf)
        bbuf[nxt][nf] = *(const bf16x8*)(Bf + ((kk + 1) * 20 + nf) * 512);
    }
    const unsigned k2 = (unsigned)((kk * 32 + g * 8) * 2);
    bf16x8 a[4];
#pragma unroll
    for (int mf = 0; mf < 4; ++mf)
      a[mf] = *(const bf16x8*)((const char*)h1 + ((arow[mf] + k2) ^ swzA));
#pragma unroll
    for (int nf = 0; nf < 5; ++nf)
#pragma unroll
      for (int mf = 0; mf < 4; ++mf)
        acc[mf][nf] = __builtin_amdgcn_mfma_f32_16x16x32_bf16(
            a[mf], bbuf[cur][nf], acc[mf][nf], 0, 0, 0);
  }

  // ---- epilogue params (global, L2-hot)
  float b2c[5], g2c[5], be2c[5], w3c[5];
#pragma unroll
  for (int nf = 0; nf < 5; ++nf) {
    const int col = wc * 80 + nf * 16 + r16;
    b2c[nf]  = b2[col];
    g2c[nf]  = g2[col];
    be2c[nf] = be2[col];
    w3c[nf]  = W3[col];
  }
#pragma unroll
  for (int nf = 0; nf < 5; ++nf)
#pragma unroll
    for (int mf = 0; mf < 4; ++mf)
#pragma unroll
      for (int r = 0; r < 4; ++r)
        acc[mf][nf][r] += b2c[nf];

  // ---- LN2 stats. global row = mf*16 + g*4 + r
#pragma unroll
  for (int mf = 0; mf < 4; ++mf) {
#pragma unroll
    for (int r = 0; r < 4; ++r) {
      float s = 0.f, q = 0.f;
#pragma unroll
      for (int nf = 0; nf < 5; ++nf) {
        const float v = acc[mf][nf][r];
        s += v;
        q = fmaf(v, v, q);
      }
#pragma unroll
      for (int m = 1; m < 16; m <<= 1) {
        s += __shfl_xor(s, m);
        q += __shfl_xor(q, m);
      }
      if (r16 == 0) {
        const int rw = mf * 16 + g * 4 + r;
        part[rw][wc][0] = s;
        part[rw][wc][1] = q;
      }
    }
  }
  __syncthreads();

  // ---- LN2 apply + leaky + dot W3
#pragma unroll
  for (int mf = 0; mf < 4; ++mf) {
#pragma unroll
    for (int r = 0; r < 4; ++r) {
      const int rw = mf * 16 + g * 4 + r;
      const float s = part[rw][0][0] + part[rw][1][0] +
                      part[rw][2][0] + part[rw][3][0];
      const float q = part[rw][0][1] + part[rw][1][1] +
                      part[rw][2][1] + part[rw][3][1];
      const float mu2  = s * (1.f / 320.f);
      const float var2 = q * (1.f / 320.f) - mu2 * mu2;
      const float rs2  = rsqrtf(var2 + LN_EPS);
      const float murs2 = mu2 * rs2;
      float dsum = 0.f;
#pragma unroll
      for (int nf = 0; nf < 5; ++nf) {
        float v = fmaf(fmaf(acc[mf][nf][r], rs2, -murs2), g2c[nf], be2c[nf]);
        v = fmaxf(v, SLOPE * v);
        dsum = fmaf(v, w3c[nf], dsum);
      }
#pragma unroll
      for (int m = 1; m < 16; m <<= 1)
        dsum += __shfl_xor(dsum, m);
      if (r16 == 0)
        pdot[rw][wc] = dsum;
    }
  }
  __syncthreads();

  if (tid < 64) {
    const float tot = pdot[tid][0] + pdot[tid][1] + pdot[tid][2] +
                      pdot[tid][3] + b3[0];
    out[i * 512 + j0 + tid] = fabsf(tot);
  }
}

// ---------------------------------------------------------------------------
extern "C" void kernel_launch(void* const* d_in, const int* in_sizes, int n_in,
                              void* d_out, int out_size, void* d_ws, size_t ws_size,
                              hipStream_t stream) {
  const float* robot  = (const float*)d_in[0];
  const float* object = (const float*)d_in[1];
  const float* lang   = (const float*)d_in[2];
  const float* W1  = (const float*)d_in[3];
  const float* b1  = (const float*)d_in[4];
  const float* g1  = (const float*)d_in[5];
  const float* be1 = (const float*)d_in[6];
  const float* W2  = (const float*)d_in[7];
  const float* b2  = (const float*)d_in[8];
  const float* g2  = (const float*)d_in[9];
  const float* be2 = (const float*)d_in[10];
  const float* W3  = (const float*)d_in[11];
  const float* b3  = (const float*)d_in[12];
  float* out = (float*)d_out;

  float* U     = (float*)d_ws;            // 512*320
  float* V     = U + 512 * 320;           // 512*320
  float* stats = V + 512 * 320;           // 2048
  __hip_bfloat16* W2F = (__hip_bfloat16*)(stats + 2048);  // 320*320 (frag-major)

  prep_kernel<<<1124, 320, 0, stream>>>(robot, object, lang, W1, b1, W2,
                                        U, V, stats, W2F);
  fused_main<<<dim3(512, 8), 256, 0, stream>>>(U, V, W2F, stats,
                                               g1, be1, b2, g2, be2, W3, b3,
                                               out);
}